// Round 1
// baseline (2752.499 us; speedup 1.0000x reference)
//
#include <hip/hip_runtime.h>

typedef __attribute__((ext_vector_type(8))) short short8;
typedef __attribute__((ext_vector_type(4))) float floatx4;

#define SCALE_F 0.17677669529663687f

__device__ __forceinline__ unsigned short f2bf(float f) {
  union { float f; unsigned u; } v; v.f = f;
  unsigned u = v.u;
  u += 0x7fffu + ((u >> 16) & 1u);   // round-to-nearest-even
  return (unsigned short)(u >> 16);
}

// C[M,N] = A[M,K] @ B[K,N] + bias ; A fp32 or bf16, B fp32 (converted), C fp32 or bf16
// M % 128 == 0, N % 128 == 0, K % 32 == 0 (holds: 100352, 2304/768, 768)
template<bool A_BF16, bool OUT_F32>
__global__ __launch_bounds__(256)
void gemm_k(const void* __restrict__ Ap, const float* __restrict__ B,
            const float* __restrict__ bias, void* __restrict__ Cp,
            int M, int N, int K) {
  __shared__ __align__(16) unsigned short As[128][40];   // [m][k], +8 pad
  __shared__ __align__(16) unsigned short BsT[128][40];  // [n][k], +8 pad
  const int tid  = threadIdx.x;
  const int wave = tid >> 6, lane = tid & 63;
  const int quad = lane >> 4, l15 = lane & 15;
  const int waveM = (wave >> 1) * 64, waveN = (wave & 1) * 64;
  const long tileM = blockIdx.x, tileN = blockIdx.y;
  floatx4 acc[4][4] = {};
  const float* Af = (const float*)Ap;
  const unsigned short* Ab = (const unsigned short*)Ap;
  const long Abase = tileM * 128 * (long)K;
  const long Bcol  = tileN * 128;

  for (int k0 = 0; k0 < K; k0 += 32) {
    #pragma unroll
    for (int it = 0; it < 2; ++it) {
      int e = tid * 8 + it * 2048;
      // ---- stage A tile (128 x 32) ----
      int row = e >> 5, kk = e & 31;
      long off = Abase + (long)row * K + k0 + kk;
      short8 v;
      if (A_BF16) {
        v = *(const short8*)(Ab + off);
      } else {
        floatx4 a0 = *(const floatx4*)(Af + off);
        floatx4 a1 = *(const floatx4*)(Af + off + 4);
        #pragma unroll
        for (int i = 0; i < 4; ++i) { v[i] = (short)f2bf(a0[i]); v[4 + i] = (short)f2bf(a1[i]); }
      }
      *(short8*)&As[row][kk] = v;
      // ---- stage B tile transposed (32 x 128 -> [n][k]) ----
      int kr = e >> 7, n0 = e & 127;
      long boff = (long)(k0 + kr) * N + Bcol + n0;
      floatx4 b0 = *(const floatx4*)(B + boff);
      floatx4 b1 = *(const floatx4*)(B + boff + 4);
      #pragma unroll
      for (int j = 0; j < 4; ++j) BsT[n0 + j][kr] = f2bf(b0[j]);
      #pragma unroll
      for (int j = 0; j < 4; ++j) BsT[n0 + 4 + j][kr] = f2bf(b1[j]);
    }
    __syncthreads();
    short8 aF[4], bF[4];
    #pragma unroll
    for (int mt = 0; mt < 4; ++mt) aF[mt] = *(const short8*)&As[waveM + mt * 16 + l15][quad * 8];
    #pragma unroll
    for (int nt = 0; nt < 4; ++nt) bF[nt] = *(const short8*)&BsT[waveN + nt * 16 + l15][quad * 8];
    #pragma unroll
    for (int mt = 0; mt < 4; ++mt)
      #pragma unroll
      for (int nt = 0; nt < 4; ++nt)
        acc[mt][nt] = __builtin_amdgcn_mfma_f32_16x16x32_bf16(aF[mt], bF[nt], acc[mt][nt], 0, 0, 0);
    __syncthreads();
  }

  float bv[4];
  #pragma unroll
  for (int nt = 0; nt < 4; ++nt) bv[nt] = bias[Bcol + waveN + nt * 16 + l15];
  #pragma unroll
  for (int mt = 0; mt < 4; ++mt)
    #pragma unroll
    for (int nt = 0; nt < 4; ++nt)
      #pragma unroll
      for (int r = 0; r < 4; ++r) {
        long rg = tileM * 128 + waveM + mt * 16 + quad * 4 + r;
        long cg = Bcol + waveN + nt * 16 + l15;
        float val = acc[mt][nt][r] + bv[nt];
        if (OUT_F32) ((float*)Cp)[rg * N + cg] = val;
        else         ((unsigned short*)Cp)[rg * N + cg] = f2bf(val);
      }
}

// One wave per (window-batch b, head h). N=49 padded to 64, hd=32.
// qkv laid out [b*49+t][3*768] with q at col h*32+d, k at 768+h*32+d, v at 1536+h*32+d.
__global__ __launch_bounds__(256)
void attn_k(const unsigned short* __restrict__ qkv, const float* __restrict__ mask,
            const float* __restrict__ bias_table, unsigned short* __restrict__ attn_out) {
  __shared__ __align__(16) unsigned short P[4][64][72];  // per-wave P tile, [i][j], +8 pad
  const int wave = threadIdx.x >> 6, lane = threadIdx.x & 63;
  const int quad = lane >> 4, l15 = lane & 15;
  const int flat = blockIdx.x * 4 + wave;   // 0 .. 49151
  const int b = flat / 24, h = flat % 24;

  const unsigned short* qbase = qkv + (long)b * 49 * 2304 + h * 32;
  const unsigned short* kbase = qbase + 768;
  const unsigned short* vbase = qbase + 1536;

  // Q fragments (A-layout: m=l15, k=quad*8+j), K fragments (B-layout: n=l15, k=quad*8+j)
  short8 qF[4], kF[4];
  #pragma unroll
  for (int mt = 0; mt < 4; ++mt) {
    int m = mt * 16 + l15; int me = m < 49 ? m : 48;
    qF[mt] = *(const short8*)(qbase + (long)me * 2304 + quad * 8);
  }
  #pragma unroll
  for (int nt = 0; nt < 4; ++nt) {
    int n = nt * 16 + l15; int ne = n < 49 ? n : 48;
    kF[nt] = *(const short8*)(kbase + (long)ne * 2304 + quad * 8);
  }

  floatx4 sc[4][4] = {};
  #pragma unroll
  for (int mt = 0; mt < 4; ++mt)
    #pragma unroll
    for (int nt = 0; nt < 4; ++nt)
      sc[mt][nt] = __builtin_amdgcn_mfma_f32_16x16x32_bf16(qF[mt], kF[nt], sc[mt][nt], 0, 0, 0);

  // fused scale + rel-bias + mask + row softmax (row lives across 16 lanes of this quad)
  const int w = b & 63;
  const float* mrow = mask + (long)w * 49 * 49;
  #pragma unroll
  for (int mt = 0; mt < 4; ++mt)
    #pragma unroll
    for (int r = 0; r < 4; ++r) {
      int i = mt * 16 + quad * 4 + r;
      bool iv = i < 49;
      int ri = i / 7, ci = i % 7;
      float vals[4];
      float vmax = -1e30f;
      #pragma unroll
      for (int nt = 0; nt < 4; ++nt) {
        int j = nt * 16 + l15;
        float v = -1e30f;
        if (iv && j < 49) {
          int rj = j / 7, cj = j % 7;
          int idx = (ri - rj + 6) * 13 + (ci - cj + 6);
          v = sc[mt][nt][r] * SCALE_F + bias_table[idx * 24 + h] + mrow[i * 49 + j];
        }
        vals[nt] = v;
        vmax = fmaxf(vmax, v);
      }
      #pragma unroll
      for (int d = 1; d < 16; d <<= 1) vmax = fmaxf(vmax, __shfl_xor(vmax, d));
      float sum = 0.f;
      #pragma unroll
      for (int nt = 0; nt < 4; ++nt) { float e = __expf(vals[nt] - vmax); vals[nt] = e; sum += e; }
      #pragma unroll
      for (int d = 1; d < 16; d <<= 1) sum += __shfl_xor(sum, d);
      float inv = 1.0f / sum;
      #pragma unroll
      for (int nt = 0; nt < 4; ++nt)
        P[wave][i][nt * 16 + l15] = f2bf(vals[nt] * inv);
    }
  __syncthreads();

  // PV: A = P (A-layout from LDS), B = V (n=d, k=j)
  floatx4 o[4][2] = {};
  #pragma unroll
  for (int kt = 0; kt < 2; ++kt) {
    short8 pF[4];
    #pragma unroll
    for (int mt = 0; mt < 4; ++mt)
      pF[mt] = *(const short8*)&P[wave][mt * 16 + l15][kt * 32 + quad * 8];
    short8 vF[2];
    #pragma unroll
    for (int nt = 0; nt < 2; ++nt) {
      short8 t;
      #pragma unroll
      for (int jj = 0; jj < 8; ++jj) {
        int j = kt * 32 + quad * 8 + jj; int je = j < 49 ? j : 48;  // P==0 for j>=49
        t[jj] = (short)vbase[(long)je * 2304 + nt * 16 + l15];
      }
      vF[nt] = t;
    }
    #pragma unroll
    for (int mt = 0; mt < 4; ++mt)
      #pragma unroll
      for (int nt = 0; nt < 2; ++nt)
        o[mt][nt] = __builtin_amdgcn_mfma_f32_16x16x32_bf16(pF[mt], vF[nt], o[mt][nt], 0, 0, 0);
  }

  unsigned short* obase = attn_out + (long)b * 49 * 768 + h * 32;
  #pragma unroll
  for (int mt = 0; mt < 4; ++mt)
    #pragma unroll
    for (int nt = 0; nt < 2; ++nt)
      #pragma unroll
      for (int r = 0; r < 4; ++r) {
        int i = mt * 16 + quad * 4 + r;
        if (i < 49) obase[(long)i * 768 + nt * 16 + l15] = f2bf(o[mt][nt][r]);
      }
}

extern "C" void kernel_launch(void* const* d_in, const int* in_sizes, int n_in,
                              void* d_out, int out_size, void* d_ws, size_t ws_size,
                              hipStream_t stream) {
  const float* x          = (const float*)d_in[0];
  const float* mask       = (const float*)d_in[1];
  const float* qkv_w      = (const float*)d_in[2];
  const float* qkv_b      = (const float*)d_in[3];
  const float* proj_w     = (const float*)d_in[4];
  const float* proj_b     = (const float*)d_in[5];
  const float* bias_table = (const float*)d_in[6];
  float* out = (float*)d_out;

  unsigned short* qkv  = (unsigned short*)d_ws;                 // 100352 x 2304 bf16 = 462.4 MB
  unsigned short* attn = qkv + (size_t)100352 * 2304;           // 100352 x 768  bf16 = 154.1 MB

  // K1: QKV projection
  gemm_k<false, false><<<dim3(784, 18), 256, 0, stream>>>(x, qkv_w, qkv_b, qkv, 100352, 2304, 768);
  // K2: windowed attention, one wave per (b, h)
  attn_k<<<12288, 256, 0, stream>>>(qkv, mask, bias_table, attn);
  // K3: output projection
  gemm_k<true, true><<<dim3(784, 6), 256, 0, stream>>>(attn, proj_w, proj_b, out, 100352, 768, 768);
}

// Round 2
// 1499.971 us; speedup vs baseline: 1.8350x; 1.8350x over previous
//
#include <hip/hip_runtime.h>

typedef __attribute__((ext_vector_type(8))) short short8;
typedef __attribute__((ext_vector_type(4))) float floatx4;
typedef __attribute__((ext_vector_type(4))) unsigned short ushort4v;

#define SCALE_F 0.17677669529663687f

__device__ __forceinline__ unsigned short f2bf(float f) {
  union { float f; unsigned u; } v; v.f = f;
  unsigned u = v.u;
  u += 0x7fffu + ((u >> 16) & 1u);   // round-to-nearest-even
  return (unsigned short)(u >> 16);
}

__device__ __forceinline__ void gld_lds16(const void* g, void* l) {
  __builtin_amdgcn_global_load_lds((const __attribute__((address_space(1))) void*)g,
                                   (__attribute__((address_space(3))) void*)l, 16, 0, 0);
}

// fp32 -> bf16 elementwise (n % 8 == 0)
__global__ __launch_bounds__(256)
void cvt_bf16_k(const float* __restrict__ src, unsigned short* __restrict__ dst, long n) {
  long i = ((long)blockIdx.x * 256 + threadIdx.x) * 8;
  if (i >= n) return;
  floatx4 a0 = *(const floatx4*)(src + i);
  floatx4 a1 = *(const floatx4*)(src + i + 4);
  short8 v;
  #pragma unroll
  for (int j = 0; j < 4; ++j) { v[j] = (short)f2bf(a0[j]); v[4 + j] = (short)f2bf(a1[j]); }
  *(short8*)(dst + i) = v;
}

// W[K][N] fp32 -> Wt[N][K] bf16 (K,N % 64 == 0)
__global__ __launch_bounds__(256)
void transcvt_k(const float* __restrict__ W, unsigned short* __restrict__ Wt, int K, int N) {
  __shared__ float t[64][65];
  const int n0 = blockIdx.x * 64, k0 = blockIdx.y * 64;
  const int tx = threadIdx.x & 15, ty = threadIdx.x >> 4;
  #pragma unroll
  for (int r = 0; r < 4; ++r) {
    floatx4 v = *(const floatx4*)&W[(long)(k0 + ty + r * 16) * N + n0 + tx * 4];
    #pragma unroll
    for (int j = 0; j < 4; ++j) t[ty + r * 16][tx * 4 + j] = v[j];
  }
  __syncthreads();
  #pragma unroll
  for (int r = 0; r < 4; ++r) {
    ushort4v o;
    #pragma unroll
    for (int j = 0; j < 4; ++j) o[j] = f2bf(t[tx * 4 + j][ty + r * 16]);
    *(ushort4v*)&Wt[(long)(n0 + ty + r * 16) * K + k0 + tx * 4] = o;
  }
}

// C[M,N] = A[M,K] @ Bt[N,K]^T + bias ; A,Bt bf16 row-major, C fp32 or bf16.
// M,N % 128 == 0, K % 32 == 0. m97-style: global_load_lds width-16 staging.
template<bool OUT_F32>
__global__ __launch_bounds__(256)
void gemm_bt(const unsigned short* __restrict__ A, const unsigned short* __restrict__ Bt,
             const float* __restrict__ bias, void* __restrict__ Cp,
             int M, int N, int K) {
  __shared__ __align__(16) unsigned short As[128 * 32];  // [m][k] contiguous, no pad
  __shared__ __align__(16) unsigned short Bs[128 * 32];  // [n][k] contiguous, no pad
  const int tid  = threadIdx.x;
  const int wave = tid >> 6, lane = tid & 63;
  const int quad = lane >> 4, l15 = lane & 15;
  const int waveM = (wave >> 1) * 64, waveN = (wave & 1) * 64;
  const int tileN = blockIdx.x, tileM = blockIdx.y;
  const int rA = lane >> 2;          // 0..15 row within 16-row chunk
  const int kA = (lane & 3) * 8;     // 0,8,16,24 (8 bf16 = 16 B per lane)
  const unsigned short* Ag = A  + ((long)tileM * 128 + wave * 32 + rA) * K + kA;
  const unsigned short* Bg = Bt + ((long)tileN * 128 + wave * 32 + rA) * K + kA;
  unsigned short* AsW = &As[(wave * 32) * 32];  // wave-uniform chunk base; HW adds lane*16B
  unsigned short* BsW = &Bs[(wave * 32) * 32];
  floatx4 acc[4][4] = {};

  for (int k0 = 0; k0 < K; k0 += 32) {
    gld_lds16(Ag + k0,            AsW);
    gld_lds16(Ag + k0 + 16 * K,   AsW + 16 * 32);
    gld_lds16(Bg + k0,            BsW);
    gld_lds16(Bg + k0 + 16 * K,   BsW + 16 * 32);
    __syncthreads();
    short8 aF[4], bF[4];
    #pragma unroll
    for (int mt = 0; mt < 4; ++mt) aF[mt] = *(const short8*)&As[(waveM + mt * 16 + l15) * 32 + quad * 8];
    #pragma unroll
    for (int nt = 0; nt < 4; ++nt) bF[nt] = *(const short8*)&Bs[(waveN + nt * 16 + l15) * 32 + quad * 8];
    #pragma unroll
    for (int mt = 0; mt < 4; ++mt)
      #pragma unroll
      for (int nt = 0; nt < 4; ++nt)
        acc[mt][nt] = __builtin_amdgcn_mfma_f32_16x16x32_bf16(aF[mt], bF[nt], acc[mt][nt], 0, 0, 0);
    __syncthreads();
  }

  float bv[4];
  #pragma unroll
  for (int nt = 0; nt < 4; ++nt) bv[nt] = bias[tileN * 128 + waveN + nt * 16 + l15];
  #pragma unroll
  for (int mt = 0; mt < 4; ++mt)
    #pragma unroll
    for (int nt = 0; nt < 4; ++nt)
      #pragma unroll
      for (int r = 0; r < 4; ++r) {
        long rg = (long)tileM * 128 + waveM + mt * 16 + quad * 4 + r;
        long cg = (long)tileN * 128 + waveN + nt * 16 + l15;
        float val = acc[mt][nt][r] + bv[nt];
        if (OUT_F32) ((float*)Cp)[rg * N + cg] = val;
        else         ((unsigned short*)Cp)[rg * N + cg] = f2bf(val);
      }
}

// One wave per (window-batch b, head h). N=49 padded to 64, hd=32.
__global__ __launch_bounds__(256)
void attn_k(const unsigned short* __restrict__ qkv, const float* __restrict__ mask,
            const float* __restrict__ bias_table, unsigned short* __restrict__ attn_out) {
  __shared__ __align__(16) unsigned short P[4][64][72];
  const int wave = threadIdx.x >> 6, lane = threadIdx.x & 63;
  const int quad = lane >> 4, l15 = lane & 15;
  const int flat = blockIdx.x * 4 + wave;
  const int b = flat / 24, h = flat % 24;

  const unsigned short* qbase = qkv + (long)b * 49 * 2304 + h * 32;
  const unsigned short* kbase = qbase + 768;
  const unsigned short* vbase = qbase + 1536;

  short8 qF[4], kF[4];
  #pragma unroll
  for (int mt = 0; mt < 4; ++mt) {
    int m = mt * 16 + l15; int me = m < 49 ? m : 48;
    qF[mt] = *(const short8*)(qbase + (long)me * 2304 + quad * 8);
  }
  #pragma unroll
  for (int nt = 0; nt < 4; ++nt) {
    int n = nt * 16 + l15; int ne = n < 49 ? n : 48;
    kF[nt] = *(const short8*)(kbase + (long)ne * 2304 + quad * 8);
  }

  floatx4 sc[4][4] = {};
  #pragma unroll
  for (int mt = 0; mt < 4; ++mt)
    #pragma unroll
    for (int nt = 0; nt < 4; ++nt)
      sc[mt][nt] = __builtin_amdgcn_mfma_f32_16x16x32_bf16(qF[mt], kF[nt], sc[mt][nt], 0, 0, 0);

  const int w = b & 63;
  const float* mrow = mask + (long)w * 49 * 49;
  #pragma unroll
  for (int mt = 0; mt < 4; ++mt)
    #pragma unroll
    for (int r = 0; r < 4; ++r) {
      int i = mt * 16 + quad * 4 + r;
      bool iv = i < 49;
      int ri = i / 7, ci = i % 7;
      float vals[4];
      float vmax = -1e30f;
      #pragma unroll
      for (int nt = 0; nt < 4; ++nt) {
        int j = nt * 16 + l15;
        float v = -1e30f;
        if (iv && j < 49) {
          int rj = j / 7, cj = j % 7;
          int idx = (ri - rj + 6) * 13 + (ci - cj + 6);
          v = sc[mt][nt][r] * SCALE_F + bias_table[idx * 24 + h] + mrow[i * 49 + j];
        }
        vals[nt] = v;
        vmax = fmaxf(vmax, v);
      }
      #pragma unroll
      for (int d = 1; d < 16; d <<= 1) vmax = fmaxf(vmax, __shfl_xor(vmax, d));
      float sum = 0.f;
      #pragma unroll
      for (int nt = 0; nt < 4; ++nt) { float e = __expf(vals[nt] - vmax); vals[nt] = e; sum += e; }
      #pragma unroll
      for (int d = 1; d < 16; d <<= 1) sum += __shfl_xor(sum, d);
      float inv = 1.0f / sum;
      #pragma unroll
      for (int nt = 0; nt < 4; ++nt)
        P[wave][i][nt * 16 + l15] = f2bf(vals[nt] * inv);
    }
  __syncthreads();

  floatx4 o[4][2] = {};
  #pragma unroll
  for (int kt = 0; kt < 2; ++kt) {
    short8 pF[4];
    #pragma unroll
    for (int mt = 0; mt < 4; ++mt)
      pF[mt] = *(const short8*)&P[wave][mt * 16 + l15][kt * 32 + quad * 8];
    short8 vF[2];
    #pragma unroll
    for (int nt = 0; nt < 2; ++nt) {
      short8 t;
      #pragma unroll
      for (int jj = 0; jj < 8; ++jj) {
        int j = kt * 32 + quad * 8 + jj; int je = j < 49 ? j : 48;
        t[jj] = (short)vbase[(long)je * 2304 + nt * 16 + l15];
      }
      vF[nt] = t;
    }
    #pragma unroll
    for (int mt = 0; mt < 4; ++mt)
      #pragma unroll
      for (int nt = 0; nt < 2; ++nt)
        o[mt][nt] = __builtin_amdgcn_mfma_f32_16x16x32_bf16(pF[mt], vF[nt], o[mt][nt], 0, 0, 0);
  }

  unsigned short* obase = attn_out + (long)b * 49 * 768 + h * 32;
  #pragma unroll
  for (int mt = 0; mt < 4; ++mt)
    #pragma unroll
    for (int nt = 0; nt < 2; ++nt)
      #pragma unroll
      for (int r = 0; r < 4; ++r) {
        int i = mt * 16 + quad * 4 + r;
        if (i < 49) obase[(long)i * 768 + nt * 16 + l15] = f2bf(o[mt][nt][r]);
      }
}

extern "C" void kernel_launch(void* const* d_in, const int* in_sizes, int n_in,
                              void* d_out, int out_size, void* d_ws, size_t ws_size,
                              hipStream_t stream) {
  const float* x          = (const float*)d_in[0];
  const float* mask       = (const float*)d_in[1];
  const float* qkv_w      = (const float*)d_in[2];
  const float* qkv_b      = (const float*)d_in[3];
  const float* proj_w     = (const float*)d_in[4];
  const float* proj_b     = (const float*)d_in[5];
  const float* bias_table = (const float*)d_in[6];

  // Scratch layout:
  //  d_out (308 MB fp32 out): xb bf16 (154.1 MB) + qkv_wt bf16 (3.5 MB) — both dead before K3 writes d_out.
  //  d_ws: qkv bf16 (462.4 MB) + attn bf16 (154.1 MB). proj_wt reuses qkv region after attn_k consumes it.
  unsigned short* xb      = (unsigned short*)d_out;
  unsigned short* qkv_wt  = (unsigned short*)d_out + (size_t)100352 * 768;
  unsigned short* qkv     = (unsigned short*)d_ws;
  unsigned short* attn    = qkv + (size_t)100352 * 2304;
  unsigned short* proj_wt = qkv;  // written after attn_k; qkv dead by then
  float* out = (float*)d_out;

  const long nx = (long)100352 * 768;
  cvt_bf16_k<<<(nx / 8 + 255) / 256, 256, 0, stream>>>(x, xb, nx);
  transcvt_k<<<dim3(36, 12), 256, 0, stream>>>(qkv_w, qkv_wt, 768, 2304);
  // K1: QKV projection (bf16 x bf16 -> bf16)
  gemm_bt<false><<<dim3(18, 784), 256, 0, stream>>>(xb, qkv_wt, qkv_b, qkv, 100352, 2304, 768);
  // K2: windowed attention
  attn_k<<<12288, 256, 0, stream>>>(qkv, mask, bias_table, attn);
  // proj weights transpose into dead qkv region
  transcvt_k<<<dim3(12, 12), 256, 0, stream>>>(proj_w, proj_wt, 768, 768);
  // K3: output projection (bf16 x bf16 -> fp32)
  gemm_bt<true><<<dim3(6, 784), 256, 0, stream>>>(attn, proj_wt, proj_b, out, 100352, 768, 768);
}